// Round 3
// baseline (238.393 us; speedup 1.0000x reference)
//
#include <hip/hip_runtime.h>
#include <math.h>

// Regional Interaction Module — round 6: reads via global_load_lds DMA path.
//
// Evidence so far: r3 (16 blocks/CU, 58% occ), r4 (persistent 3-deep
// pipeline, 33% occ), r5 (plain stores) ALL tie at ~72 us / 2.33 TB/s,
// FETCH exactly half the input bytes, VALU 21%, VMEM issue ~1/190 cy.
// Wall is invariant to occupancy/pipelining/store hints -> a throughput
// cap in the load path (outstanding-miss capacity x latency), which every
// variant shared: plain global_load -> texture return -> VGPR writeback.
//
// This round routes ALL input reads through the global->LDS DMA engine
// (__builtin_amdgcn_global_load_lds, width=16), the one memory mechanism
// not yet tried. Each wave reads back only the LDS slice it wrote, so the
// double-buffer needs NO barriers; hand-counted vmcnt waits keep the next
// tile's 4 DMA loads in flight across the current tile's compute (no
// vmcnt(0) drain anywhere).
//
// vmcnt FIFO trace (4 DMA per tile, 3 stores per tile, per wave):
//   pref0(4), pref1(4), WAIT(4) -> retires pref0          | comp0 stores(3)
//   pref2(4), WAIT(7) -> retires pref1, leaves st0+pref2  | comp1 stores(3)
//   ... steady state: WAIT(7) retires st_{t-2}+pref_t     |
//   last tile: WAIT(3) -> retires st+pref_last, then comp.

#define HWQ_SHIFT 16             // HW/4 = 65536 float4 groups per plane
#define HWQ (1 << HWQ_SHIFT)

__device__ __forceinline__ float sigm(float x) {
    return __builtin_amdgcn_rcpf(1.0f + __expf(-x));
}

#define GLD_LDS16(gp, lp) \
    __builtin_amdgcn_global_load_lds( \
        (const __attribute__((address_space(1))) unsigned int*)(gp), \
        (__attribute__((address_space(3))) unsigned int*)(lp), 16, 0, 0)

#define WAITVM(N) asm volatile("s_waitcnt vmcnt(" #N ")" ::: "memory")

__global__ __launch_bounds__(256) void rim_kernel(
    const float* __restrict__ img,  const float* __restrict__ mask,
    const float* __restrict__ qiw,  const float* __restrict__ qib,
    const float* __restrict__ kiw,  const float* __restrict__ kib,
    const float* __restrict__ viw,  const float* __restrict__ vib,
    const float* __restrict__ qrw,  const float* __restrict__ qrb,
    const float* __restrict__ krw,  const float* __restrict__ krb,
    const float* __restrict__ vrw,  const float* __restrict__ vrb,
    const float* __restrict__ fuw,  const float* __restrict__ fub,
    float* __restrict__ out)
{
    // [dbuf][stream: img0,img1,img2,mask][group] — 32 KiB total.
    __shared__ float4 lds[2][4][256];

    // ---- uniform weight loads (scalar loads -> SGPRs) ----
    const float w_qi0 = qiw[0], w_qi1 = qiw[1], w_qi2 = qiw[2], b_qi = qib[0];
    const float w_ki0 = kiw[0], w_ki1 = kiw[1], w_ki2 = kiw[2], b_ki = kib[0];
    float w_vi[9], b_vi[3];
#pragma unroll
    for (int j = 0; j < 9; ++j) w_vi[j] = viw[j];
#pragma unroll
    for (int j = 0; j < 3; ++j) b_vi[j] = vib[j];
    const float w_qr = qrw[0], b_qr = qrb[0];
    const float w_kr = krw[0], b_kr = krb[0];
    const float w_vr = vrw[0], b_vr = vrb[0];
    float w_fu[18], b_fu[3];
#pragma unroll
    for (int j = 0; j < 18; ++j) w_fu[j] = fuw[j];
#pragma unroll
    for (int j = 0; j < 3; ++j) b_fu[j] = fub[j];

    const int tid  = threadIdx.x;
    const int wv   = tid & ~63;              // wave's slice base (uniform/wave)
    // Block covers 8 tiles x 256 groups = 2048 contiguous groups.
    // 65536/2048 = 32 blocks per batch -> whole block in one batch plane.
    const int gblk = blockIdx.x * 2048;
    const int b    = gblk >> HWQ_SHIFT;      // batch (block-uniform)
    const int hw   = (gblk & (HWQ - 1)) + tid;  // plane-relative group, tile 0

    const float4* ip4 = (const float4*)img  + ((size_t)b * 3 << HWQ_SHIFT);
    const float4* mp4 = (const float4*)mask + ((size_t)b     << HWQ_SHIFT);
    float4*       op4 = (float4*)out        + ((size_t)b * 3 << HWQ_SHIFT);

    auto compute = [&](const float4& X0q, const float4& X1q, const float4& X2q,
                       const float4& Mq, float4& O0, float4& O1, float4& O2) {
        const float* px0 = &X0q.x; const float* px1 = &X1q.x;
        const float* px2 = &X2q.x; const float* pm  = &Mq.x;
        float* po0 = &O0.x; float* po1 = &O1.x; float* po2 = &O2.x;
#pragma unroll
        for (int l = 0; l < 4; ++l) {
            const float X0 = px0[l], X1 = px1[l], X2 = px2[l], M = pm[l];

            const float q_i = b_qi + w_qi0 * X0 + w_qi1 * X1 + w_qi2 * X2;
            const float k_i = b_ki + w_ki0 * X0 + w_ki1 * X1 + w_ki2 * X2;
            const float v0  = b_vi[0] + w_vi[0] * X0 + w_vi[1] * X1 + w_vi[2] * X2;
            const float v1  = b_vi[1] + w_vi[3] * X0 + w_vi[4] * X1 + w_vi[5] * X2;
            const float v2  = b_vi[2] + w_vi[6] * X0 + w_vi[7] * X1 + w_vi[8] * X2;
            const float q_r = b_qr + w_qr * M;
            const float k_r = b_kr + w_kr * M;
            const float v_r = b_vr + w_vr * M;

            const float s_ii = sigm(q_i * k_i);
            const float s_ir = sigm(q_i * k_r);
            const float s_rr = sigm(q_r * k_r);
            const float s_ri = sigm(q_r * k_i);

            const float fi0 = s_ii * v0 + s_ir * v_r;
            const float fi1 = s_ii * v1 + s_ir * v_r;
            const float fi2 = s_ii * v2 + s_ir * v_r;
            const float fr0 = s_rr * v_r + s_ri * v0;
            const float fr1 = s_rr * v_r + s_ri * v1;
            const float fr2 = s_rr * v_r + s_ri * v2;

            po0[l] = b_fu[0] + w_fu[0]  * fi0 + w_fu[1]  * fi1 + w_fu[2]  * fi2
                             + w_fu[3]  * fr0 + w_fu[4]  * fr1 + w_fu[5]  * fr2;
            po1[l] = b_fu[1] + w_fu[6]  * fi0 + w_fu[7]  * fi1 + w_fu[8]  * fi2
                             + w_fu[9]  * fr0 + w_fu[10] * fr1 + w_fu[11] * fr2;
            po2[l] = b_fu[2] + w_fu[12] * fi0 + w_fu[13] * fi1 + w_fu[14] * fi2
                             + w_fu[15] * fr0 + w_fu[16] * fr1 + w_fu[17] * fr2;
        }
    };

    // Issue one tile's 4 DMA loads. Global addr is per-lane; LDS dest is
    // wave-uniform base + lane*16, i.e. element [wv + lane] == [tid].
#define PREF(d, t) do { \
        const float4* gp = ip4 + hw + (t) * 256; \
        GLD_LDS16(gp,            &lds[d][0][wv]); \
        GLD_LDS16(gp + HWQ,      &lds[d][1][wv]); \
        GLD_LDS16(gp + 2 * HWQ,  &lds[d][2][wv]); \
        GLD_LDS16(mp4 + hw + (t) * 256, &lds[d][3][wv]); \
    } while (0)

#define COMP(d, t) do { \
        const float4 X0q = lds[d][0][tid]; \
        const float4 X1q = lds[d][1][tid]; \
        const float4 X2q = lds[d][2][tid]; \
        const float4 Mq  = lds[d][3][tid]; \
        float4 o0, o1, o2; \
        compute(X0q, X1q, X2q, Mq, o0, o1, o2); \
        op4[hw + (t) * 256]           = o0; \
        op4[hw + (t) * 256 + HWQ]     = o1; \
        op4[hw + (t) * 256 + 2 * HWQ] = o2; \
    } while (0)

    PREF(0, 0);
    PREF(1, 1); WAITVM(4); COMP(0, 0);
    PREF(0, 2); WAITVM(7); COMP(1, 1);
    PREF(1, 3); WAITVM(7); COMP(0, 2);
    PREF(0, 4); WAITVM(7); COMP(1, 3);
    PREF(1, 5); WAITVM(7); COMP(0, 4);
    PREF(0, 6); WAITVM(7); COMP(1, 5);
    PREF(1, 7); WAITVM(7); COMP(0, 6);
                WAITVM(3); COMP(1, 7);

#undef PREF
#undef COMP
}

extern "C" void kernel_launch(void* const* d_in, const int* in_sizes, int n_in,
                              void* d_out, int out_size, void* d_ws, size_t ws_size,
                              hipStream_t stream) {
    const float* img  = (const float*)d_in[0];
    const float* mask = (const float*)d_in[1];
    const float* qiw  = (const float*)d_in[2];
    const float* qib  = (const float*)d_in[3];
    const float* kiw  = (const float*)d_in[4];
    const float* kib  = (const float*)d_in[5];
    const float* viw  = (const float*)d_in[6];
    const float* vib  = (const float*)d_in[7];
    const float* qrw  = (const float*)d_in[8];
    const float* qrb  = (const float*)d_in[9];
    const float* krw  = (const float*)d_in[10];
    const float* krb  = (const float*)d_in[11];
    const float* vrw  = (const float*)d_in[12];
    const float* vrb  = (const float*)d_in[13];
    const float* fuw  = (const float*)d_in[14];
    const float* fub  = (const float*)d_in[15];
    float* out = (float*)d_out;

    // 2,097,152 float4 groups; 2048 per block -> 1024 blocks x 256 threads.
    rim_kernel<<<1024, 256, 0, stream>>>(img, mask, qiw, qib, kiw, kib, viw, vib,
                                         qrw, qrb, krw, krb, vrw, vrb, fuw, fub, out);
}